// Round 7
// baseline (153.051 us; speedup 1.0000x reference)
//
#include <hip/hip_runtime.h>
#include <math.h>

#define BATCH 16384
#define NSETS 1024
#define ALPHA 0.001f
#define BETA  0.001f

// R17 = R16 with the GEMM K-tile halved: BK 128 -> 64, KITER 8 -> 16.
// Rationale (counters): masses is latency/barrier-bound at Occupancy 16.3%
// (~1.3 blocks/CU resident; LDS 64.5 KB caps 2/CU). This is exactly the
// guide's m132 regression configuration (BK=128, 64KB LDS, 508 TF) vs the
// m97 structure (BK=64, 32KB LDS, 874-912 TF) on the SAME 2-barrier loop.
// With BK=64: LDS 32KB -> 4 blocks/CU, 2x co-resident blocks hide the
// per-iteration vmcnt-drain barriers. Same total MFMA count, same staging
// pattern, same (verified-equivalent) bank-conflict-free read distribution.
// fp8 k-interleave moves from 128B groups to 64B groups:
//   per 16-dword group: o(8B chunk 0..7) -> n = ((o&3)<<1)|((o>>2)&1)
// so 16B chunk q = original k-chunks (q, q+4) adjacent -> one ds_read_b128
// feeds both MFMA k-steps. bce pd / moeb permute updated to match.
// Everything else (A32 rowsum epilogue -- R15-proven FREE, cpart reduce,
// stripe-last + global-last protocols, XCD swizzle, 2 dispatches): verbatim.
#define BM 128
#define BN 128
#define BK 64
#define NSTRIPE (BATCH / BM)            // 128 m-stripes
#define NBLK_N  (NSETS / BN)            // 8 n-blocks per stripe
#define GEMM_BLOCKS (NSTRIPE * NBLK_N)  // 1024
#define KITER (NSETS / BK)              // 16

typedef __attribute__((ext_vector_type(4))) float f32x4;
typedef __attribute__((ext_vector_type(2))) long s64x2;

// ws float-index layout (R10/R13 layout):
//   [0] mr_sum  [1] global counter (uint)  [2] ms_sum  [3] pad   (zeroed k1 b0)
//   [4 .. 4+2048)            bce per-block partials (write-once)
//   [4096 .. 4096+16384)     row sums (atomics; zeroed by k1 blocks 0..2047)
//   [20480 .. 20480+128)     per-stripe counters (uint; zeroed by k1 block 1)
//   [24576 .. 24576+65536)   c_part[64][1024] moebius colsum partials (w-once)
// ws byte layout:
//   [393216 ..)              pred_fp8 (16.8 MB, 64B-group k-interleaved)
//   [393216 + 16777216 ..)   moeb_fp8 (1 MB, 64B-group k-interleaved)
#define BCEP_OFF   4
#define ROWSUM_OFF 4096
#define STRIPE_OFF 20480
#define CPART_OFF  24576
#define WS_PREDF8_OFF 393216
#define WS_MOEBF8_OFF (393216 + BATCH * NSETS)

__device__ __forceinline__ void gld16(const void* g, void* l) {
    __builtin_amdgcn_global_load_lds(
        (const __attribute__((address_space(1))) unsigned int*)g,
        (__attribute__((address_space(3))) unsigned int*)l, 16, 0, 0);
}

// 4 fp32 -> 4 fp8 e4m3 (OCP) packed in an int, HW converter
__device__ __forceinline__ int pk_fp8x4(float a, float b, float c, float d) {
    int v = 0;
    v = __builtin_amdgcn_cvt_pk_fp8_f32(a, b, v, 0);   // low word
    v = __builtin_amdgcn_cvt_pk_fp8_f32(c, d, v, 1);   // high word
    return v;
}

// dword-in-row permutation for the 64B-group k-chunk interleave: within each
// 64B k-group (16 dwords), 8B chunk o -> n = ((o&3)<<1)|((o>>2)&1), so a
// lane's two MFMA k-chunks (q, q+4) land ADJACENT -> b128 fragment reads.
__device__ __forceinline__ int permute_dword64(int d) {
    const int g = d >> 4;          // 64B group (16 dwords)
    const int w = d & 15;
    const int o = w >> 1;          // 8B chunk 0..7
    const int p = w & 1;
    const int n = ((o & 3) << 1) | ((o >> 2) & 1);
    return (g << 4) | (n << 1) | p;
}

// relaxed agent-scope load: bypasses (possibly stale) L1/L2, no cache inval
__device__ __forceinline__ float coh_load(const float* p) {
    return __hip_atomic_load(p, __ATOMIC_RELAXED, __HIP_MEMORY_SCOPE_AGENT);
}

__device__ __forceinline__ float block_reduce_sum(float v, float* sm) {
    #pragma unroll
    for (int off = 32; off > 0; off >>= 1) v += __shfl_down(v, off, 64);
    const int lane = threadIdx.x & 63;
    const int wid  = threadIdx.x >> 6;
    if (lane == 0) sm[wid] = v;
    __syncthreads();
    const int nw = blockDim.x >> 6;
    v = (threadIdx.x < nw) ? sm[threadIdx.x] : 0.0f;
    if (wid == 0) {
        #pragma unroll
        for (int off = 32; off > 0; off >>= 1) v += __shfl_down(v, off, 64);
    }
    return v;  // valid in thread 0
}

// -------- k1: BCE (fp32-exact) + pred->fp8 (64B-group k-interleaved) + ws
// zeroing; blocks >= 2048 convert moebius->fp8 and emit write-once colsum
// partials. 8-row MLP group: all 16 P/T float4 + 8 tidx loads in flight
// before compute; one __logf per 4 elements via the product trick.
__global__ __launch_bounds__(256)
void bce_convert_kernel(const float* __restrict__ pred,
                        const float* __restrict__ membership,
                        const int*   __restrict__ tidx,
                        const float* __restrict__ moeb,
                        float*       __restrict__ ws,
                        int*         __restrict__ pred_f8,
                        int*         __restrict__ moeb_f8) {
    const int tid = threadIdx.x;
    const int bi  = blockIdx.x;
    if (bi >= 2048) {   // moebius: 64 blocks; block j handles rows j*16..+15
        const int j    = bi - 2048;
        const int base = j * 4096 + tid;
        float4 csum = make_float4(0.f, 0.f, 0.f, 0.f);
        #pragma unroll
        for (int k = 0; k < 16; k++) {
            const int i = base + k * 256;        // row j*16+k, col4 = tid
            const float4 v = ((const float4*)moeb)[i];
            const int row = i >> 8;
            moeb_f8[(row << 8) | permute_dword64(i & 255)] =
                pk_fp8x4(v.x, v.y, v.z, v.w);
            csum.x += v.x; csum.y += v.y; csum.z += v.z; csum.w += v.w;
        }
        ((float4*)(ws + CPART_OFF))[j * 256 + tid] = csum;  // write-once
        return;
    }
    // zero accumulators for the masses kernel (stream order guarantees vis.)
    if (tid < 8)                    ws[ROWSUM_OFF + bi * 8 + tid] = 0.0f;
    if (bi == 0 && tid >= 8 && tid < 12) ws[tid - 8] = 0.0f;
    if (bi == 1 && tid < NSTRIPE)   ws[STRIPE_OFF + tid] = 0.0f;

    __shared__ float sm[4];
    const float eps = 1e-7f;
    const float hi  = 1.0f - 1e-7f;
    const int   pd  = permute_dword64(tid);   // hoisted: same for all rows
    float acc = 0.0f;

    float4 P[8], T[8];
    int rows[8];
    // issue all 8 pred loads
    #pragma unroll
    for (int k = 0; k < 8; k++) {
        rows[k] = bi + k * 2048;
        P[k] = ((const float4*)pred)[rows[k] * 256 + tid];
    }
    // issue all 8 membership gathers (cls is block-uniform -> s_load)
    #pragma unroll
    for (int k = 0; k < 8; k++) {
        const int cls = tidx[rows[k]];
        T[k] = ((const float4*)membership)[(cls << 8) + tid];
    }
    // compute + fp8 store; 1 logf per 4 elements (product in [1e-28,1]:
    // always fp32-normal, unconditionally safe)
    #pragma unroll
    for (int k = 0; k < 8; k++) {
        float cp[4];
        cp[0] = fminf(fmaxf(P[k].x, eps), hi);
        cp[1] = fminf(fmaxf(P[k].y, eps), hi);
        cp[2] = fminf(fmaxf(P[k].z, eps), hi);
        cp[3] = fminf(fmaxf(P[k].w, eps), hi);
        pred_f8[(rows[k] << 8) | pd] = pk_fp8x4(cp[0], cp[1], cp[2], cp[3]);
        const float x0 = (T[k].x > 0.5f) ? cp[0] : (1.0f - cp[0]);
        const float x1 = (T[k].y > 0.5f) ? cp[1] : (1.0f - cp[1]);
        const float x2 = (T[k].z > 0.5f) ? cp[2] : (1.0f - cp[2]);
        const float x3 = (T[k].w > 0.5f) ? cp[3] : (1.0f - cp[3]);
        acc += __logf((x0 * x1) * (x2 * x3));
    }
    const float tot = block_reduce_sum(acc, sm);
    if (tid == 0) ws[BCEP_OFF + bi] = tot;    // write-once partial
}

// -------- k2: masses = p_fp8 @ moeb_fp8^T via MFMA (BK=64, 32KB LDS ->
// 4 blocks/CU); distributed exact fp32 rowsum partials for ms (inline
// epilogue, FREE per R15); stripe-last folds; global-last finalizes.
__global__ __launch_bounds__(256, 4)
void masses_mfma_kernel(const unsigned char* __restrict__ A,   // pred_fp8
                        const unsigned char* __restrict__ Bm,  // moeb_fp8
                        const float* __restrict__ A32,         // pred fp32
                        float* __restrict__ ws,
                        float* __restrict__ out) {
    __shared__ __align__(16) unsigned char Alds[2][BM * BK];  // 2 x 8 KB
    __shared__ __align__(16) unsigned char Blds[2][BN * BK];  // 2 x 8 KB
    __shared__ float sm[4];
    __shared__ unsigned flag;

    const int tid  = threadIdx.x;
    const int lane = tid & 63;
    const int w    = tid >> 6;
    const int wm   = w >> 1;
    const int wn   = w & 1;
    const int lr   = lane & 15;
    const int q    = lane >> 4;

    // XCD-aware swizzle (performance heuristic only)
    const int id     = blockIdx.x;
    const int xcd    = id & 7;
    const int slot   = id >> 3;                 // 0..127 within XCD
    const int grp    = slot >> 3;               // 0..15
    const int stripe = xcd * 16 + grp;
    const int nblk   = slot & 7;
    const int m0     = stripe * BM;
    const int n0     = nblk * BN;               // also this block's k-chunk base

    f32x4 acc[4][4];
    #pragma unroll
    for (int i = 0; i < 4; i++)
        #pragma unroll
        for (int j = 0; j < 4; j++) acc[i][j] = (f32x4){0.f, 0.f, 0.f, 0.f};

    // staging: 512 slots of 16B per 8KB tile; thread t covers slots
    // s = t + j*256; slot s -> row r = s>>2, 16B-chunk c = s&3 holds global
    // chunk c ^ ((r>>1)&3)  (fp8 k-tile row = 64 B = BK)
    size_t aoff[2], boff[2];
    unsigned loff[2];
    #pragma unroll
    for (int j = 0; j < 2; j++) {
        const int s  = tid + j * 256;
        const int r  = s >> 2;
        const int gc = (s & 3) ^ ((r >> 1) & 3);
        aoff[j] = (size_t)(m0 + r) * NSETS + gc * 16;
        boff[j] = (size_t)(n0 + r) * NSETS + gc * 16;
        loff[j] = (unsigned)(s * 16);
    }
    const int sw = (lr >> 1) & 3;  // fragment-read swizzle term

    // prologue: issue stage of tile 0 into buffer 0
    #pragma unroll
    for (int j = 0; j < 2; j++) {
        gld16(A  + aoff[j], &Alds[0][loff[j]]);
        gld16(Bm + boff[j], &Blds[0][loff[j]]);
    }

    for (int it = 0; it < KITER; it++) {
        const int cur = it & 1;
        __syncthreads();   // drains vmcnt -> buf[cur] ready; WAR-safe for nxt
        if (it + 1 < KITER) {   // issue next tile: in flight during the MFMAs
            const int nk = (it + 1) * BK;
            #pragma unroll
            for (int j = 0; j < 2; j++) {
                gld16(A  + aoff[j] + nk, &Alds[cur ^ 1][loff[j]]);
                gld16(Bm + boff[j] + nk, &Blds[cur ^ 1][loff[j]]);
            }
        }
        // compute on buf[cur]: one b128 read per fragment covers both MFMA
        // k-steps (chunk q = original k-chunks q and q+4, adjacent)
        {
            const int off = 16 * (q ^ sw);
            s64x2 a[4], b[4];
            #pragma unroll
            for (int mi = 0; mi < 4; mi++)
                a[mi] = *(const s64x2*)&Alds[cur][(wm * 64 + mi * 16 + lr) * BK + off];
            #pragma unroll
            for (int ni = 0; ni < 4; ni++)
                b[ni] = *(const s64x2*)&Blds[cur][(wn * 64 + ni * 16 + lr) * BK + off];
            #pragma unroll
            for (int mi = 0; mi < 4; mi++)
                #pragma unroll
                for (int ni = 0; ni < 4; ni++) {
                    acc[mi][ni] = __builtin_amdgcn_mfma_f32_16x16x32_fp8_fp8(
                        a[mi][0], b[ni][0], acc[mi][ni], 0, 0, 0);
                    acc[mi][ni] = __builtin_amdgcn_mfma_f32_16x16x32_fp8_fp8(
                        a[mi][1], b[ni][1], acc[mi][ni], 0, 0, 0);
                }
        }
    }

    // ---- mr epilogue ----
    float mrpart = 0.0f;
    #pragma unroll
    for (int mi = 0; mi < 4; mi++)
        #pragma unroll
        for (int ni = 0; ni < 4; ni++)
            #pragma unroll
            for (int r = 0; r < 4; r++)
                mrpart += fmaxf(-acc[mi][ni][r], 0.0f);
    const float mrtot = block_reduce_sum(mrpart, sm);  // has a barrier inside
    if (tid == 0) atomicAdd(&ws[0], mrtot);            // device-scope atomic

    // ---- distributed exact fp32 rowsum partial: k-chunk [n0, n0+128) ----
    __syncthreads();                 // all MFMA reads done -> Alds reusable
    float* clds = (float*)Alds;      // [0..1024) seg partials, [1024..1152) c
    {
        const int col = tid & 31;    // f4-col within the 128-float chunk
        const int seg = tid >> 5;    // 8 segments of 8 c_part rows each
        float4 cs = make_float4(0.f, 0.f, 0.f, 0.f);
        #pragma unroll
        for (int j = 0; j < 8; j++) {   // prev-dispatch data: plain loads OK
            const float4 v = ((const float4*)(ws + CPART_OFF))
                                 [(seg * 8 + j) * 256 + (n0 >> 2) + col];
            cs.x += v.x; cs.y += v.y; cs.z += v.z; cs.w += v.w;
        }
        ((float4*)clds)[seg * 32 + col] = cs;
    }
    __syncthreads();
    if (tid < 32) {
        float4 t = make_float4(0.f, 0.f, 0.f, 0.f);
        #pragma unroll
        for (int s2 = 0; s2 < 8; s2++) {
            const float4 v = ((const float4*)clds)[s2 * 32 + tid];
            t.x += v.x; t.y += v.y; t.z += v.z; t.w += v.w;
        }
        ((float4*)clds)[256 + tid] = t;   // final c chunk at floats [1024..)
    }
    __syncthreads();
    {
        const float eps = 1e-7f;
        const float hi  = 1.0f - 1e-7f;
        const int r    = tid >> 1;        // row within stripe
        const int half = tid & 1;         // 64 k each
        const float4* prow = (const float4*)(A32 + (size_t)(m0 + r) * NSETS
                                             + n0 + half * 64);
        const float4* crow = (const float4*)(clds + 1024 + half * 64);
        float s = 0.0f;
        #pragma unroll
        for (int k = 0; k < 16; k++) {
            float4 pv = prow[k];
            const float4 cv = crow[k];
            pv.x = fminf(fmaxf(pv.x, eps), hi);
            pv.y = fminf(fmaxf(pv.y, eps), hi);
            pv.z = fminf(fmaxf(pv.z, eps), hi);
            pv.w = fminf(fmaxf(pv.w, eps), hi);
            s += pv.x * cv.x + pv.y * cv.y + pv.z * cv.z + pv.w * cv.w;
        }
        s += __shfl_xor(s, 1, 64);        // combine the two k-halves
        if (half == 0) atomicAdd(&ws[ROWSUM_OFF + m0 + r], s);
    }

    // ---- stripe-last: fold |rowsum-1| (fence-free counter protocol) ----
    __syncthreads();   // drains each wave's vmcnt -> atomics at coherent point
    if (tid == 0)
        flag = (__hip_atomic_fetch_add((unsigned int*)&ws[STRIPE_OFF + stripe],
                    1u, __ATOMIC_RELAXED, __HIP_MEMORY_SCOPE_AGENT)
                == NBLK_N - 1);
    __syncthreads();
    if (flag) {
        float sms = 0.0f;
        if (tid < BM)
            sms = fabsf(coh_load(ws + ROWSUM_OFF + m0 + tid) - 1.0f);
        __syncthreads();                 // sm reuse guard
        const float mssum = block_reduce_sum(sms, sm);
        if (tid == 0) atomicAdd(&ws[2], mssum);
    }
    __syncthreads();   // drain the ms atomic before the global bump

    // ---- global-last finalize ----
    if (tid == 0)
        flag = (__hip_atomic_fetch_add((unsigned int*)&ws[1], 1u,
                    __ATOMIC_RELAXED, __HIP_MEMORY_SCOPE_AGENT)
                == GEMM_BLOCKS - 1);
    __syncthreads();
    if (flag) {
        float s_bce = 0.0f;
        #pragma unroll
        for (int k = 0; k < 2; k++) {    // prev-dispatch data: plain loads OK
            const float4 v = ((const float4*)(ws + BCEP_OFF))[tid + k * 256];
            s_bce += v.x + v.y + v.z + v.w;
        }
        __syncthreads();                 // sm reuse guard
        const float bcesum = block_reduce_sum(s_bce, sm);
        if (tid == 0) {
            const float inv = 1.0f / ((float)BATCH * (float)NSETS);
            const float bce = -bcesum * inv;
            const float mr  =  coh_load(ws + 0) * inv;
            const float ms  =  coh_load(ws + 2) / (float)BATCH;
            out[0] = bce + ALPHA * mr + BETA * ms;
            out[1] = bce;
            out[2] = mr;
            out[3] = ms;
        }
    }
}

extern "C" void kernel_launch(void* const* d_in, const int* in_sizes, int n_in,
                              void* d_out, int out_size, void* d_ws, size_t ws_size,
                              hipStream_t stream) {
    const float* pred       = (const float*)d_in[0];
    const float* membership = (const float*)d_in[1];
    const float* moebius    = (const float*)d_in[2];
    const int*   tidx       = (const int*)d_in[3];
    float* out = (float*)d_out;
    float* ws  = (float*)d_ws;
    int* pred_f8 = (int*)((char*)d_ws + WS_PREDF8_OFF);
    int* moeb_f8 = (int*)((char*)d_ws + WS_MOEBF8_OFF);

    bce_convert_kernel<<<2048 + 64, 256, 0, stream>>>(
        pred, membership, tidx, moebius, ws, pred_f8, moeb_f8);
    masses_mfma_kernel<<<GEMM_BLOCKS, 256, 0, stream>>>(
        (const unsigned char*)pred_f8, (const unsigned char*)moeb_f8,
        pred, ws, out);
}

// Round 8
// 149.979 us; speedup vs baseline: 1.0205x; 1.0205x over previous
//
#include <hip/hip_runtime.h>
#include <math.h>

#define BATCH 16384
#define NSETS 1024
#define ALPHA 0.001f
#define BETA  0.001f

// R18 = R17 with the GEMM K-loop rebuilt as a 4-buffer, counted-vmcnt
// pipeline (T3/T4 essence, guide m218: counted-vs-drain0 = +38-73%).
// Evidence: R15-R17 proved masses' 51 us is invariant to occupancy, LDS
// size, and the A32 epilogue -> the cost is the per-tile FULL DRAIN
// (__syncthreads = s_waitcnt vmcnt(0) lgkmcnt(0); s_barrier) with only ~1
// tile of MFMA to cover load latency. New loop, per tile t:
//   s_waitcnt vmcnt(12); s_barrier   // tile t's 4 loads: issued 4 tiles ago
//   compute tile t (8 ds_read_b128 + 32 MFMA; compiler handles lgkmcnt)
//   s_barrier                        // WAR: all waves done reading buf t&3
//   stage tile t+4 into buf[t&3]     // 4 gld16, stay in flight ~4 tiles
// vmcnt never drains to 0 in the main loop; epilogue peels 8/4/0.
// Raw s_barrier via asm("...":::"memory") avoids the compiler's auto-drain.
// Correctness: per-thread vmcnt counts its own 4 gld16/tile oldest-first
// (m135); the ready-barrier AFTER the wait publishes all threads' loads;
// uniform control flow at every barrier. All else (bce k1, fp8 64B-group
// interleave, fragment reads, A32 rowsum epilogue, protocols): R17-verbatim.
#define BM 128
#define BN 128
#define BK 64
#define NSTRIPE (BATCH / BM)            // 128 m-stripes
#define NBLK_N  (NSETS / BN)            // 8 n-blocks per stripe
#define GEMM_BLOCKS (NSTRIPE * NBLK_N)  // 1024
#define KITER (NSETS / BK)              // 16

typedef __attribute__((ext_vector_type(4))) float f32x4;
typedef __attribute__((ext_vector_type(2))) long s64x2;

// ws float-index layout (R10/R13 layout):
//   [0] mr_sum  [1] global counter (uint)  [2] ms_sum  [3] pad   (zeroed k1 b0)
//   [4 .. 4+2048)            bce per-block partials (write-once)
//   [4096 .. 4096+16384)     row sums (atomics; zeroed by k1 blocks 0..2047)
//   [20480 .. 20480+128)     per-stripe counters (uint; zeroed by k1 block 1)
//   [24576 .. 24576+65536)   c_part[64][1024] moebius colsum partials (w-once)
// ws byte layout:
//   [393216 ..)              pred_fp8 (16.8 MB, 64B-group k-interleaved)
//   [393216 + 16777216 ..)   moeb_fp8 (1 MB, 64B-group k-interleaved)
#define BCEP_OFF   4
#define ROWSUM_OFF 4096
#define STRIPE_OFF 20480
#define CPART_OFF  24576
#define WS_PREDF8_OFF 393216
#define WS_MOEBF8_OFF (393216 + BATCH * NSETS)

__device__ __forceinline__ void gld16(const void* g, void* l) {
    __builtin_amdgcn_global_load_lds(
        (const __attribute__((address_space(1))) unsigned int*)g,
        (__attribute__((address_space(3))) unsigned int*)l, 16, 0, 0);
}

// 4 fp32 -> 4 fp8 e4m3 (OCP) packed in an int, HW converter
__device__ __forceinline__ int pk_fp8x4(float a, float b, float c, float d) {
    int v = 0;
    v = __builtin_amdgcn_cvt_pk_fp8_f32(a, b, v, 0);   // low word
    v = __builtin_amdgcn_cvt_pk_fp8_f32(c, d, v, 1);   // high word
    return v;
}

// dword-in-row permutation for the 64B-group k-chunk interleave: within each
// 64B k-group (16 dwords), 8B chunk o -> n = ((o&3)<<1)|((o>>2)&1), so a
// lane's two MFMA k-chunks (q, q+4) land ADJACENT -> b128 fragment reads.
__device__ __forceinline__ int permute_dword64(int d) {
    const int g = d >> 4;          // 64B group (16 dwords)
    const int w = d & 15;
    const int o = w >> 1;          // 8B chunk 0..7
    const int p = w & 1;
    const int n = ((o & 3) << 1) | ((o >> 2) & 1);
    return (g << 4) | (n << 1) | p;
}

// relaxed agent-scope load: bypasses (possibly stale) L1/L2, no cache inval
__device__ __forceinline__ float coh_load(const float* p) {
    return __hip_atomic_load(p, __ATOMIC_RELAXED, __HIP_MEMORY_SCOPE_AGENT);
}

__device__ __forceinline__ float block_reduce_sum(float v, float* sm) {
    #pragma unroll
    for (int off = 32; off > 0; off >>= 1) v += __shfl_down(v, off, 64);
    const int lane = threadIdx.x & 63;
    const int wid  = threadIdx.x >> 6;
    if (lane == 0) sm[wid] = v;
    __syncthreads();
    const int nw = blockDim.x >> 6;
    v = (threadIdx.x < nw) ? sm[threadIdx.x] : 0.0f;
    if (wid == 0) {
        #pragma unroll
        for (int off = 32; off > 0; off >>= 1) v += __shfl_down(v, off, 64);
    }
    return v;  // valid in thread 0
}

// -------- k1: BCE (fp32-exact) + pred->fp8 (64B-group k-interleaved) + ws
// zeroing; blocks >= 2048 convert moebius->fp8 and emit write-once colsum
// partials. 8-row MLP group: all 16 P/T float4 + 8 tidx loads in flight
// before compute; one __logf per 4 elements via the product trick.
__global__ __launch_bounds__(256)
void bce_convert_kernel(const float* __restrict__ pred,
                        const float* __restrict__ membership,
                        const int*   __restrict__ tidx,
                        const float* __restrict__ moeb,
                        float*       __restrict__ ws,
                        int*         __restrict__ pred_f8,
                        int*         __restrict__ moeb_f8) {
    const int tid = threadIdx.x;
    const int bi  = blockIdx.x;
    if (bi >= 2048) {   // moebius: 64 blocks; block j handles rows j*16..+15
        const int j    = bi - 2048;
        const int base = j * 4096 + tid;
        float4 csum = make_float4(0.f, 0.f, 0.f, 0.f);
        #pragma unroll
        for (int k = 0; k < 16; k++) {
            const int i = base + k * 256;        // row j*16+k, col4 = tid
            const float4 v = ((const float4*)moeb)[i];
            const int row = i >> 8;
            moeb_f8[(row << 8) | permute_dword64(i & 255)] =
                pk_fp8x4(v.x, v.y, v.z, v.w);
            csum.x += v.x; csum.y += v.y; csum.z += v.z; csum.w += v.w;
        }
        ((float4*)(ws + CPART_OFF))[j * 256 + tid] = csum;  // write-once
        return;
    }
    // zero accumulators for the masses kernel (stream order guarantees vis.)
    if (tid < 8)                    ws[ROWSUM_OFF + bi * 8 + tid] = 0.0f;
    if (bi == 0 && tid >= 8 && tid < 12) ws[tid - 8] = 0.0f;
    if (bi == 1 && tid < NSTRIPE)   ws[STRIPE_OFF + tid] = 0.0f;

    __shared__ float sm[4];
    const float eps = 1e-7f;
    const float hi  = 1.0f - 1e-7f;
    const int   pd  = permute_dword64(tid);   // hoisted: same for all rows
    float acc = 0.0f;

    float4 P[8], T[8];
    int rows[8];
    // issue all 8 pred loads
    #pragma unroll
    for (int k = 0; k < 8; k++) {
        rows[k] = bi + k * 2048;
        P[k] = ((const float4*)pred)[rows[k] * 256 + tid];
    }
    // issue all 8 membership gathers (cls is block-uniform -> s_load)
    #pragma unroll
    for (int k = 0; k < 8; k++) {
        const int cls = tidx[rows[k]];
        T[k] = ((const float4*)membership)[(cls << 8) + tid];
    }
    // compute + fp8 store; 1 logf per 4 elements (product in [1e-28,1]:
    // always fp32-normal, unconditionally safe)
    #pragma unroll
    for (int k = 0; k < 8; k++) {
        float cp[4];
        cp[0] = fminf(fmaxf(P[k].x, eps), hi);
        cp[1] = fminf(fmaxf(P[k].y, eps), hi);
        cp[2] = fminf(fmaxf(P[k].z, eps), hi);
        cp[3] = fminf(fmaxf(P[k].w, eps), hi);
        pred_f8[(rows[k] << 8) | pd] = pk_fp8x4(cp[0], cp[1], cp[2], cp[3]);
        const float x0 = (T[k].x > 0.5f) ? cp[0] : (1.0f - cp[0]);
        const float x1 = (T[k].y > 0.5f) ? cp[1] : (1.0f - cp[1]);
        const float x2 = (T[k].z > 0.5f) ? cp[2] : (1.0f - cp[2]);
        const float x3 = (T[k].w > 0.5f) ? cp[3] : (1.0f - cp[3]);
        acc += __logf((x0 * x1) * (x2 * x3));
    }
    const float tot = block_reduce_sum(acc, sm);
    if (tid == 0) ws[BCEP_OFF + bi] = tot;    // write-once partial
}

// stage K-tile (kt) into buffer (buf): 4 gld16 per thread (2 A + 2 B)
#define MM_STAGE(buf, kt) {                                         \
    const int nk_ = (kt) * BK;                                      \
    gld16(A  + aoff[0] + nk_, &Alds[buf][loff[0]]);                 \
    gld16(A  + aoff[1] + nk_, &Alds[buf][loff[1]]);                 \
    gld16(Bm + boff[0] + nk_, &Blds[buf][loff[0]]);                 \
    gld16(Bm + boff[1] + nk_, &Blds[buf][loff[1]]);                 \
}

// compute one K-tile from buffer (buf): 8 ds_read_b128 + 32 MFMA
#define MM_COMPUTE(buf) {                                           \
    const int off_ = 16 * (q ^ sw);                                 \
    s64x2 a_[4], b_[4];                                             \
    _Pragma("unroll")                                               \
    for (int mi = 0; mi < 4; mi++)                                  \
        a_[mi] = *(const s64x2*)                                    \
            &Alds[buf][(wm * 64 + mi * 16 + lr) * BK + off_];       \
    _Pragma("unroll")                                               \
    for (int ni = 0; ni < 4; ni++)                                  \
        b_[ni] = *(const s64x2*)                                    \
            &Blds[buf][(wn * 64 + ni * 16 + lr) * BK + off_];       \
    _Pragma("unroll")                                               \
    for (int mi = 0; mi < 4; mi++)                                  \
        _Pragma("unroll")                                           \
        for (int ni = 0; ni < 4; ni++) {                            \
            acc[mi][ni] = __builtin_amdgcn_mfma_f32_16x16x32_fp8_fp8( \
                a_[mi][0], b_[ni][0], acc[mi][ni], 0, 0, 0);        \
            acc[mi][ni] = __builtin_amdgcn_mfma_f32_16x16x32_fp8_fp8( \
                a_[mi][1], b_[ni][1], acc[mi][ni], 0, 0, 0);        \
        }                                                           \
}

// -------- k2: masses = p_fp8 @ moeb_fp8^T via MFMA (BK=64, 4-buffer
// counted-vmcnt pipeline, depth-4 prefetch, ~66KB LDS -> 2 blocks/CU);
// distributed exact fp32 rowsum partials for ms (inline epilogue, FREE per
// R15); stripe-last folds; global-last finalizes.
__global__ __launch_bounds__(256, 2)
void masses_mfma_kernel(const unsigned char* __restrict__ A,   // pred_fp8
                        const unsigned char* __restrict__ Bm,  // moeb_fp8
                        const float* __restrict__ A32,         // pred fp32
                        float* __restrict__ ws,
                        float* __restrict__ out) {
    __shared__ __align__(16) unsigned char Alds[4][BM * BK];  // 4 x 8 KB
    __shared__ __align__(16) unsigned char Blds[4][BN * BK];  // 4 x 8 KB
    __shared__ float sm[4];
    __shared__ unsigned flag;

    const int tid  = threadIdx.x;
    const int lane = tid & 63;
    const int w    = tid >> 6;
    const int wm   = w >> 1;
    const int wn   = w & 1;
    const int lr   = lane & 15;
    const int q    = lane >> 4;

    // XCD-aware swizzle (performance heuristic only)
    const int id     = blockIdx.x;
    const int xcd    = id & 7;
    const int slot   = id >> 3;                 // 0..127 within XCD
    const int grp    = slot >> 3;               // 0..15
    const int stripe = xcd * 16 + grp;
    const int nblk   = slot & 7;
    const int m0     = stripe * BM;
    const int n0     = nblk * BN;               // also this block's k-chunk base

    f32x4 acc[4][4];
    #pragma unroll
    for (int i = 0; i < 4; i++)
        #pragma unroll
        for (int j = 0; j < 4; j++) acc[i][j] = (f32x4){0.f, 0.f, 0.f, 0.f};

    // staging: 512 slots of 16B per 8KB tile; thread t covers slots
    // s = t + j*256; slot s -> row r = s>>2, 16B-chunk c = s&3 holds global
    // chunk c ^ ((r>>1)&3)  (fp8 k-tile row = 64 B = BK)
    size_t aoff[2], boff[2];
    unsigned loff[2];
    #pragma unroll
    for (int j = 0; j < 2; j++) {
        const int s  = tid + j * 256;
        const int r  = s >> 2;
        const int gc = (s & 3) ^ ((r >> 1) & 3);
        aoff[j] = (size_t)(m0 + r) * NSETS + gc * 16;
        boff[j] = (size_t)(n0 + r) * NSETS + gc * 16;
        loff[j] = (unsigned)(s * 16);
    }
    const int sw = (lr >> 1) & 3;  // fragment-read swizzle term

    // prologue: fill the 4-deep pipeline (16 gld16 outstanding per thread)
    MM_STAGE(0, 0)
    MM_STAGE(1, 1)
    MM_STAGE(2, 2)
    MM_STAGE(3, 3)

    // main loop: counted vmcnt (12 = 3 tiles x 4 loads stay in flight);
    // tile t's loads were issued 4 tiles ago -> ~4 tiles of MFMA cover.
    for (int t = 0; t <= 12; ++t) {
        asm volatile("s_waitcnt vmcnt(12)\n\ts_barrier" ::: "memory");
        MM_COMPUTE(t & 3)
        asm volatile("s_barrier" ::: "memory");   // WAR: buf[t&3] free
        if (t + 4 < KITER) MM_STAGE(t & 3, t + 4)
    }
    // epilogue peel: outstanding 12 -> 8 -> 4 -> 0
    asm volatile("s_waitcnt vmcnt(8)\n\ts_barrier" ::: "memory");
    MM_COMPUTE(1)                                  // tile 13
    asm volatile("s_barrier" ::: "memory");
    asm volatile("s_waitcnt vmcnt(4)\n\ts_barrier" ::: "memory");
    MM_COMPUTE(2)                                  // tile 14
    asm volatile("s_barrier" ::: "memory");
    asm volatile("s_waitcnt vmcnt(0)\n\ts_barrier" ::: "memory");
    MM_COMPUTE(3)                                  // tile 15

    // ---- mr epilogue ----
    float mrpart = 0.0f;
    #pragma unroll
    for (int mi = 0; mi < 4; mi++)
        #pragma unroll
        for (int ni = 0; ni < 4; ni++)
            #pragma unroll
            for (int r = 0; r < 4; r++)
                mrpart += fmaxf(-acc[mi][ni][r], 0.0f);
    const float mrtot = block_reduce_sum(mrpart, sm);  // has a barrier inside
    if (tid == 0) atomicAdd(&ws[0], mrtot);            // device-scope atomic

    // ---- distributed exact fp32 rowsum partial: k-chunk [n0, n0+128) ----
    __syncthreads();                 // all MFMA reads done -> Alds reusable
    float* clds = (float*)Alds;      // [0..1024) seg partials, [1024..1152) c
    {
        const int col = tid & 31;    // f4-col within the 128-float chunk
        const int seg = tid >> 5;    // 8 segments of 8 c_part rows each
        float4 cs = make_float4(0.f, 0.f, 0.f, 0.f);
        #pragma unroll
        for (int j = 0; j < 8; j++) {   // prev-dispatch data: plain loads OK
            const float4 v = ((const float4*)(ws + CPART_OFF))
                                 [(seg * 8 + j) * 256 + (n0 >> 2) + col];
            cs.x += v.x; cs.y += v.y; cs.z += v.z; cs.w += v.w;
        }
        ((float4*)clds)[seg * 32 + col] = cs;
    }
    __syncthreads();
    if (tid < 32) {
        float4 t = make_float4(0.f, 0.f, 0.f, 0.f);
        #pragma unroll
        for (int s2 = 0; s2 < 8; s2++) {
            const float4 v = ((const float4*)clds)[s2 * 32 + tid];
            t.x += v.x; t.y += v.y; t.z += v.z; t.w += v.w;
        }
        ((float4*)clds)[256 + tid] = t;   // final c chunk at floats [1024..)
    }
    __syncthreads();
    {
        const float eps = 1e-7f;
        const float hi  = 1.0f - 1e-7f;
        const int r    = tid >> 1;        // row within stripe
        const int half = tid & 1;         // 64 k each
        const float4* prow = (const float4*)(A32 + (size_t)(m0 + r) * NSETS
                                             + n0 + half * 64);
        const float4* crow = (const float4*)(clds + 1024 + half * 64);
        float s = 0.0f;
        #pragma unroll
        for (int k = 0; k < 16; k++) {
            float4 pv = prow[k];
            const float4 cv = crow[k];
            pv.x = fminf(fmaxf(pv.x, eps), hi);
            pv.y = fminf(fmaxf(pv.y, eps), hi);
            pv.z = fminf(fmaxf(pv.z, eps), hi);
            pv.w = fminf(fmaxf(pv.w, eps), hi);
            s += pv.x * cv.x + pv.y * cv.y + pv.z * cv.z + pv.w * cv.w;
        }
        s += __shfl_xor(s, 1, 64);        // combine the two k-halves
        if (half == 0) atomicAdd(&ws[ROWSUM_OFF + m0 + r], s);
    }

    // ---- stripe-last: fold |rowsum-1| (fence-free counter protocol) ----
    __syncthreads();   // drains each wave's vmcnt -> atomics at coherent point
    if (tid == 0)
        flag = (__hip_atomic_fetch_add((unsigned int*)&ws[STRIPE_OFF + stripe],
                    1u, __ATOMIC_RELAXED, __HIP_MEMORY_SCOPE_AGENT)
                == NBLK_N - 1);
    __syncthreads();
    if (flag) {
        float sms = 0.0f;
        if (tid < BM)
            sms = fabsf(coh_load(ws + ROWSUM_OFF + m0 + tid) - 1.0f);
        __syncthreads();                 // sm reuse guard
        const float mssum = block_reduce_sum(sms, sm);
        if (tid == 0) atomicAdd(&ws[2], mssum);
    }
    __syncthreads();   // drain the ms atomic before the global bump

    // ---- global-last finalize ----
    if (tid == 0)
        flag = (__hip_atomic_fetch_add((unsigned int*)&ws[1], 1u,
                    __ATOMIC_RELAXED, __HIP_MEMORY_SCOPE_AGENT)
                == GEMM_BLOCKS - 1);
    __syncthreads();
    if (flag) {
        float s_bce = 0.0f;
        #pragma unroll
        for (int k = 0; k < 2; k++) {    // prev-dispatch data: plain loads OK
            const float4 v = ((const float4*)(ws + BCEP_OFF))[tid + k * 256];
            s_bce += v.x + v.y + v.z + v.w;
        }
        __syncthreads();                 // sm reuse guard
        const float bcesum = block_reduce_sum(s_bce, sm);
        if (tid == 0) {
            const float inv = 1.0f / ((float)BATCH * (float)NSETS);
            const float bce = -bcesum * inv;
            const float mr  =  coh_load(ws + 0) * inv;
            const float ms  =  coh_load(ws + 2) / (float)BATCH;
            out[0] = bce + ALPHA * mr + BETA * ms;
            out[1] = bce;
            out[2] = mr;
            out[3] = ms;
        }
    }
}

extern "C" void kernel_launch(void* const* d_in, const int* in_sizes, int n_in,
                              void* d_out, int out_size, void* d_ws, size_t ws_size,
                              hipStream_t stream) {
    const float* pred       = (const float*)d_in[0];
    const float* membership = (const float*)d_in[1];
    const float* moebius    = (const float*)d_in[2];
    const int*   tidx       = (const int*)d_in[3];
    float* out = (float*)d_out;
    float* ws  = (float*)d_ws;
    int* pred_f8 = (int*)((char*)d_ws + WS_PREDF8_OFF);
    int* moeb_f8 = (int*)((char*)d_ws + WS_MOEBF8_OFF);

    bce_convert_kernel<<<2048 + 64, 256, 0, stream>>>(
        pred, membership, tidx, moebius, ws, pred_f8, moeb_f8);
    masses_mfma_kernel<<<GEMM_BLOCKS, 256, 0, stream>>>(
        (const unsigned char*)pred_f8, (const unsigned char*)moeb_f8,
        pred, ws, out);
}